// Round 2
// baseline (297.190 us; speedup 1.0000x reference)
//
#include <hip/hip_runtime.h>

// EdgeDecoder: out[e] = w2 . relu(W1 @ concat(z_sotu[row[e]], z_taxon[col[e]]) + b1) + b2
// E=1e6, H=128, K=2H=256. Per harness header: float tensors are fp32, indices int32,
// output fp32. We downconvert to bf16 in-kernel for MFMA (2% rel threshold allows it).
//
// Design:
//  - GEMM: C[M=128 hidden][N=edges] = W1 @ Z^T via mfma_f32_32x32x16_bf16.
//    Edges on N: C-layout col=lane&31=edge makes layer-2 an in-lane reduce.
//  - Block = 256 thr (4 waves), tile = 128 edges. Wave w owns hidden rows [32w,32w+32):
//    W1 A-frags (converted fp32->bf16) persistent in 64 VGPRs.
//  - Z tile: fp32 gather (coalesced float4, 16 lanes per 512B row-half) -> bf16 in reg
//    -> ds_write_b128, XOR-swizzled (chunk pos q = c ^ (r&31)) so both the b128 writes
//    and the B-frag ds_read_b128 are bank-balanced.
//  - Epilogue: in-lane relu+fma over 16 hidden, shfl_xor(32) pairs complementary hidden
//    of the SAME edge, cross-wave combine via 2 KB LDS (aliased into zs). LDS 64 KB ->
//    2 blocks/CU.

#define HID    128
#define KDIM   256
#define TILE_E 128

typedef __attribute__((ext_vector_type(8)))  short  bf16x8;   // 8 bf16 = 4 VGPRs
typedef __attribute__((ext_vector_type(16))) float  f32x16;   // 32x32 MFMA accumulator

__device__ __forceinline__ unsigned short f2bf(float f) {
    unsigned u = __float_as_uint(f);
    u += 0x7fffu + ((u >> 16) & 1u);   // round-to-nearest-even
    return (unsigned short)(u >> 16);
}

__device__ __forceinline__ bf16x8 pack8(float4 a, float4 b) {
    bf16x8 f;
    f[0] = (short)f2bf(a.x); f[1] = (short)f2bf(a.y);
    f[2] = (short)f2bf(a.z); f[3] = (short)f2bf(a.w);
    f[4] = (short)f2bf(b.x); f[5] = (short)f2bf(b.y);
    f[6] = (short)f2bf(b.z); f[7] = (short)f2bf(b.w);
    return f;
}

__global__ __launch_bounds__(256, 2)
void edge_mlp_kernel(const float* __restrict__ z_sotu,   // [100000,128] fp32
                     const float* __restrict__ z_taxon,  // [50000,128] fp32
                     const int*   __restrict__ row,      // [E] int32
                     const int*   __restrict__ col,      // [E] int32
                     const float* __restrict__ w1,       // [128,256] fp32
                     const float* __restrict__ b1,       // [128]
                     const float* __restrict__ w2,       // [128]
                     const float* __restrict__ b2,       // [1]
                     float*       __restrict__ out,      // [E] fp32
                     int E)
{
    __shared__ __align__(16) unsigned short zs[TILE_E * KDIM];   // 64 KB bf16, swizzled

    const int tid  = threadIdx.x;
    const int wave = tid >> 6;
    const int lane = tid & 63;
    const int l31  = lane & 31;
    const int hlf  = lane >> 5;
    const long long e0 = (long long)blockIdx.x * TILE_E;

    // ---- Stage Z tile: wave w stages tile rows [32w, 32w+32) (= 64 row-halves).
    // lane = rhl*16 + ch: 16 lanes cover one 512 B row-half; lane ch handles chunk ch
    // (8 floats -> 8 bf16 = 16 B). 16 passes x 4 row-halves per wave.
    {
        const int ch  = lane & 15;     // chunk within row-half
        const int rhl = lane >> 4;     // row-half within pass (0..3)
        #pragma unroll
        for (int pass = 0; pass < 16; ++pass) {
            const int rh = pass * 4 + rhl;          // row-half within wave slice (0..63)
            const int r  = 32 * wave + (rh >> 1);   // tile row (= edge slot)
            const int hh = rh & 1;                  // 0 = sotu half, 1 = taxon half
            long long e = e0 + r;
            if (e >= E) e = E - 1;                  // tail clamp (store is guarded)
            const int idx = hh ? col[e] : row[e];
            const float* src = (hh ? z_taxon : z_sotu) + (long long)idx * HID + ch * 8;
            const float4 a = *(const float4*)(src);
            const float4 b = *(const float4*)(src + 4);
            const int c = hh * 16 + ch;             // chunk index in concat row (0..31)
            const int q = c ^ (r & 31);             // swizzled position
            *(bf16x8*)(zs + r * KDIM + q * 8) = pack8(a, b);
        }
    }

    // ---- W1 A-fragments (independent of LDS; overlaps staging latency).
    // A layout: lane holds A[m=lane&31][k = hlf*8 + j]; frag ks covers k = 16*ks..+16.
    bf16x8 afrag[16];
    {
        const float* wrow = w1 + (32 * wave + l31) * KDIM + hlf * 8;
        #pragma unroll
        for (int ks = 0; ks < 16; ++ks) {
            const float4 a = *(const float4*)(wrow + ks * 16);
            const float4 b = *(const float4*)(wrow + ks * 16 + 4);
            afrag[ks] = pack8(a, b);
        }
    }
    __syncthreads();

    // ---- K-loop: 4 edge n-tiles x 16 k-steps. B layout: lane holds B[n=lane&31][k=hlf*8+j].
    f32x16 acc[4] = {};
    #pragma unroll
    for (int ks = 0; ks < 16; ++ks) {
        #pragma unroll
        for (int nt = 0; nt < 4; ++nt) {
            const int el = 32 * nt + l31;                 // edge slot within tile
            const int q  = (2 * ks + hlf) ^ l31;          // swizzled chunk position
            bf16x8 bfrag = *(const bf16x8*)(zs + el * KDIM + q * 8);
            acc[nt] = __builtin_amdgcn_mfma_f32_32x32x16_bf16(afrag[ks], bfrag, acc[nt], 0, 0, 0);
        }
    }

    __syncthreads();                  // all b-frag reads done before aliasing zs
    float* partial = (float*)zs;      // [4][TILE_E] cross-wave partials (2 KB)

    // b1/w2 for this lane's 16 hidden rows: hid = 32w + (r&3) + 8*(r>>2) + 4*hlf
    float b1v[16], w2v[16];
    #pragma unroll
    for (int g = 0; g < 4; ++g) {
        const int hb = 32 * wave + 8 * g + 4 * hlf;
        const float4 bb = *(const float4*)(b1 + hb);
        const float4 ww = *(const float4*)(w2 + hb);
        b1v[4*g+0] = bb.x; b1v[4*g+1] = bb.y; b1v[4*g+2] = bb.z; b1v[4*g+3] = bb.w;
        w2v[4*g+0] = ww.x; w2v[4*g+1] = ww.y; w2v[4*g+2] = ww.z; w2v[4*g+3] = ww.w;
    }

    // Lane holds 16 hidden of edge (32*nt + l31); mirror lane (^32) holds the
    // complementary 16 of the SAME edge -> one shfl_xor completes this wave's 32-hid slice.
    #pragma unroll
    for (int nt = 0; nt < 4; ++nt) {
        float p = 0.0f;
        #pragma unroll
        for (int r = 0; r < 16; ++r) {
            const float h = fmaxf(acc[nt][r] + b1v[r], 0.0f);
            p = fmaf(h, w2v[r], p);
        }
        p += __shfl_xor(p, 32, 64);
        if (hlf == 0)
            partial[wave * TILE_E + 32 * nt + l31] = p;
    }
    __syncthreads();

    if (tid < TILE_E) {
        const long long e = e0 + tid;
        if (e < E) {
            out[e] = partial[0 * TILE_E + tid] + partial[1 * TILE_E + tid]
                   + partial[2 * TILE_E + tid] + partial[3 * TILE_E + tid]
                   + b2[0];
        }
    }
}

extern "C" void kernel_launch(void* const* d_in, const int* in_sizes, int n_in,
                              void* d_out, int out_size, void* d_ws, size_t ws_size,
                              hipStream_t stream) {
    const float* z_sotu  = (const float*)d_in[0];
    const float* z_taxon = (const float*)d_in[1];
    const int*   row     = (const int*)d_in[2];
    const int*   col     = (const int*)d_in[3];
    const float* w1      = (const float*)d_in[4];
    const float* b1      = (const float*)d_in[5];
    const float* w2      = (const float*)d_in[6];
    const float* b2      = (const float*)d_in[7];
    float*       out     = (float*)d_out;

    const int E = in_sizes[2];
    const int nblocks = (E + TILE_E - 1) / TILE_E;
    hipLaunchKernelGGL(edge_mlp_kernel, dim3(nblocks), dim3(256), 0, stream,
                       z_sotu, z_taxon, row, col, w1, b1, w2, b2, out, E);
}